// Round 2
// baseline (79.815 us; speedup 1.0000x reference)
//
#include <hip/hip_runtime.h>

// Problem constants (match reference)
#define B_  8
#define L_  512
#define C_  6
#define N_  (B_ * L_)
#define K_  9
#define BIGF 1e10f

// Output layout (flat float32, concatenated in return order)
#define NK        (N_ * K_)               // 36864
#define OFF_DKNN  0
#define OFF_SRC   (NK)
#define OFF_DST   (2 * NK)
#define OFF_VALID (3 * NK)
#define OFF_GLB   (4 * NK)
#define GLB_PER   (2 * L_ - 1)            // 1023
#define GLB_TOT   (2 * B_ * GLB_PER)      // 16368
#define OFF_SEQ   (OFF_GLB + GLB_TOT)
#define SEQ_PER   (2 * (L_ - 2))          // 1020
#define SEQ_TOT   (2 * B_ * SEQ_PER)      // 16320

// 512 threads = 8 waves; 4 rows per block, 2 waves per row (256 cols each).
// Grid doubles to 1024 blocks -> 3 blocks/CU (LDS 50.5KB) = 24 waves/CU,
// vs the old 2 blocks/CU = 16. Per-wave main loop and selection chain halve.
#define TPB 512
#define RPB 4
#define HALF_COLS 256

// Raw staging geometry inside the 48 KB ch[] buffer:
#define XFLOATS (L_ * C_ * 3)             // 9216 floats = 36 KB of raw X
#define X4      (XFLOATS / 4)             // 2304 float4 copies
#define AP4     (L_ * C_ / 4)             // 768 int4 copies (12 KB) -> total 48 KB exact

static __device__ __forceinline__ unsigned umin32(unsigned a, unsigned b) {
    return a < b ? a : b;
}

__global__ __launch_bounds__(TPB, 6) void fused_kernel(const float* __restrict__ X,
                                                       const int* __restrict__ AP,
                                                       const int* __restrict__ S,
                                                       const int* __restrict__ sec,
                                                       float* __restrict__ out) {
    __shared__ float4 ch[C_][L_];         // 48 KB; doubles as raw staging buffer
    __shared__ int sbuf[L_];              // 2 KB
    __shared__ unsigned cand[RPB][32];    // 512 B: per-row merge candidates

    const int tid = threadIdx.x;
    const int lane = tid & 63;
    const int wv = tid >> 6;              // 0..7
    const int r = wv >> 1;                // row-in-block 0..3
    const int h = wv & 1;                 // column half 0/1
    const int row = blockIdx.x * RPB + r;
    const int base = row & ~(L_ - 1);
    const int rl = row & (L_ - 1);

    float* lds = (float*)&ch[0][0];

    // ---- Phase A: coalesced staging of this graph's X/AP/S slices ----
    {
        const float4* Xs = (const float4*)(X + (size_t)base * (C_ * 3));
        float4* L4 = (float4*)lds;
#pragma unroll
        for (int i = 0; i < 5; ++i) {               // 2304 = 4.5 * 512
            const int idx = tid + i * TPB;
            if (idx < X4) L4[idx] = Xs[idx];
        }
        const int4* As = (const int4*)(AP + (size_t)base * C_);
        int4* LA = (int4*)(lds + XFLOATS);
#pragma unroll
        for (int i = 0; i < 2; ++i) {               // 768 = 1.5 * 512
            const int idx = tid + i * TPB;
            if (idx < AP4) LA[idx] = As[idx];
        }
        sbuf[tid] = S[base + tid];
    }

    // ---- static glb/seq edge lists (first 32 blocks' threads) ----
    {
        const int gt = blockIdx.x * TPB + tid;
        if (gt < GLB_TOT) {
            const int rr = gt / (B_ * GLB_PER);
            const int rem = gt % (B_ * GLB_PER);
            const int b = rem / GLB_PER;
            const int q = rem % GLB_PER;
            int v;
            if (rr == 0) v = (q < L_) ? 0 : (q - (L_ - 1));  // src: [0]*L ++ [1..L-1]
            else         v = (q < L_) ? q : 0;               // dst: [0..L-1] ++ [0]*(L-1)
            out[OFF_GLB + gt] = (float)(v + b * L_);
        }
        if (gt < SEQ_TOT) {
            const int rr = gt / (B_ * SEQ_PER);
            const int rem = gt % (B_ * SEQ_PER);
            const int b = rem / SEQ_PER;
            const int q = rem % SEQ_PER;
            int v;
            if (rr == 0) v = (q < L_ - 2) ? (q + 1) : (q - (L_ - 2) + 2);  // [1..510]++[2..511]
            else         v = (q < L_ - 2) ? (q + 2) : (q - (L_ - 2) + 1);  // [2..511]++[1..510]
            out[OFF_SEQ + gt] = (float)(v + b * L_);
        }
    }

    __syncthreads();

    // ---- Phase B: per-node transform from raw LDS into registers ----
    float4 rrec[C_];
    {
        const float* meF = lds + tid * 18;
        const int* apme = ((const int*)(lds + XFLOATS)) + tid * C_;
        const float bias_g = (sbuf[tid] == 0) ? BIGF : 0.0f;  // global node loses every min
#pragma unroll
        for (int c = 0; c < C_; ++c) {
            const float a = meF[3 * c], b = meF[3 * c + 1], d = meF[3 * c + 2];
            float sq = (a * a + b * b) + d * d + bias_g;
            if (apme[c] == 0) sq += BIGF;                     // padded channel loses every min
            rrec[c] = make_float4(a, b, d, sq);
        }
    }
    __syncthreads();

    // ---- Phase C: publish transformed records (overwrites raw staging) ----
#pragma unroll
    for (int c = 0; c < C_; ++c) ch[c][tid] = rrec[c];
    __syncthreads();

    // ---- row fragment: broadcast-read own record, fold -2 into coords ----
    float ax[C_], ay[C_], az[C_], sc[C_];
#pragma unroll
    for (int c = 0; c < C_; ++c) {
        const float4 q = ch[c][rl];
        ax[c] = -2.0f * q.x; ay[c] = -2.0f * q.y; az[c] = -2.0f * q.z;
        sc[c] = q.w;
    }

    // ---- distances: this wave owns cols [h*256, h*256+256), lane j strided 64 ----
    unsigned v[4];
#pragma unroll
    for (int s = 0; s < 4; ++s) {
        const int col = (h << 8) + (s << 6) + lane;
        float m = 3.0e38f;
#pragma unroll
        for (int d = 0; d < C_; ++d) {
            const float4 q = ch[d][col];
            const float t0 = fmaf(az[0], q.z, fmaf(ay[0], q.y, fmaf(ax[0], q.x, sc[0])));
            const float t1 = fmaf(az[1], q.z, fmaf(ay[1], q.y, fmaf(ax[1], q.x, sc[1])));
            const float t2 = fmaf(az[2], q.z, fmaf(ay[2], q.y, fmaf(ax[2], q.x, sc[2])));
            const float t3 = fmaf(az[3], q.z, fmaf(ay[3], q.y, fmaf(ax[3], q.x, sc[3])));
            const float t4 = fmaf(az[4], q.z, fmaf(ay[4], q.y, fmaf(ax[4], q.x, sc[4])));
            const float t5 = fmaf(az[5], q.z, fmaf(ay[5], q.y, fmaf(ax[5], q.x, sc[5])));
            const float m012 = fminf(fminf(t0, t1), t2);      // -> v_min3_f32
            const float m345 = fminf(fminf(t3, t4), t5);
            m = fminf(m, fminf(m012, m345) + q.w);
        }
        m = fmaxf(m, 0.0f);   // d2, clamped; masked pairs land >= ~1e10
        // 23-bit value prefix + 9-bit col: u32 order == (d2, col) lexicographic
        v[s] = (__float_as_uint(m) & 0xFFFFFE00u) | (unsigned)col;
    }

    // ---- stage 1: 9 rounds of stable wave argmin over this wave's 256 cols ----
    unsigned mine = 0xFFFFFFFFu;
#pragma unroll
    for (int t = 0; t < K_; ++t) {
        unsigned loc = umin32(umin32(v[0], v[1]), umin32(v[2], v[3]));
#pragma unroll
        for (int off = 32; off >= 1; off >>= 1) {
            const unsigned o = (unsigned)__shfl_xor((int)loc, off, 64);
            loc = umin32(loc, o);
        }
        if (lane == t) mine = loc;                 // lane t keeps round-t winner
#pragma unroll
        for (int s = 0; s < 4; ++s)                // remove winner (keys unique)
            v[s] = (v[s] == loc) ? 0xFFFFFFFFu : v[s];
    }

    // ---- publish per-half top-9 (lanes 9..15 publish UINT_MAX padding) ----
    if (lane < 16) cand[r][(h << 4) + lane] = mine;
    __syncthreads();

    // ---- stage 2 (h==0 wave per row): merge 18 candidates -> final top-9 ----
    if (h == 0) {
        unsigned cv = (lane < 32) ? cand[r][lane] : 0xFFFFFFFFu;
        unsigned fin = 0xFFFFFFFFu;
#pragma unroll
        for (int t = 0; t < K_; ++t) {
            unsigned loc = cv;
#pragma unroll
            for (int off = 16; off >= 1; off >>= 1) {   // candidates live in lanes 0..31
                const unsigned o = (unsigned)__shfl_xor((int)loc, off, 64);
                loc = umin32(loc, o);
            }
            if (lane == t) fin = loc;
            cv = (cv == loc) ? 0xFFFFFFFFu : cv;
        }

        // ---- epilogue: lanes 0..8 write the 4 per-edge outputs ----
        if (lane < K_) {
            const int col = (int)(fin & 511u);
            const float d2 = __uint_as_float(fin & 0xFFFFFE00u);
            const bool masked = (d2 >= 1.0e9f);        // valid pairs are < ~1e5
            const float dval = masked ? BIGF : sqrtf(d2);
            const int dst = base + col;
            const bool valid = !masked && (sec[row] == sec[dst]);
            const size_t o = (size_t)row * K_ + lane;
            out[OFF_DKNN + o]  = dval;
            out[OFF_SRC + o]   = (float)row;
            out[OFF_DST + o]   = valid ? (float)dst : -1.0f;
            out[OFF_VALID + o] = valid ? 1.0f : 0.0f;
        }
    }
}

extern "C" void kernel_launch(void* const* d_in, const int* in_sizes, int n_in,
                              void* d_out, int out_size, void* d_ws, size_t ws_size,
                              hipStream_t stream) {
    (void)in_sizes; (void)n_in; (void)out_size; (void)d_ws; (void)ws_size;
    const float* X   = (const float*)d_in[0];
    const int*   AP  = (const int*)d_in[1];
    const int*   S   = (const int*)d_in[2];
    const int*   sec = (const int*)d_in[3];
    float* out = (float*)d_out;

    hipLaunchKernelGGL(fused_kernel, dim3(N_ / RPB), dim3(TPB), 0, stream,
                       X, AP, S, sec, out);
}

// Round 3
// 73.272 us; speedup vs baseline: 1.0893x; 1.0893x over previous
//
#include <hip/hip_runtime.h>

// Problem constants (match reference)
#define B_  8
#define L_  512
#define C_  6
#define N_  (B_ * L_)
#define K_  9
#define BIGF 1e10f

// Output layout (flat float32, concatenated in return order)
#define NK        (N_ * K_)               // 36864
#define OFF_DKNN  0
#define OFF_SRC   (NK)
#define OFF_DST   (2 * NK)
#define OFF_VALID (3 * NK)
#define OFF_GLB   (4 * NK)
#define GLB_PER   (2 * L_ - 1)            // 1023
#define GLB_TOT   (2 * B_ * GLB_PER)      // 16368
#define OFF_SEQ   (OFF_GLB + GLB_TOT)
#define SEQ_PER   (2 * (L_ - 2))          // 1020
#define SEQ_TOT   (2 * B_ * SEQ_PER)      // 16320

#define TPB 512            // 8 waves = 8 rows per block
#define RPB 8

static __device__ __forceinline__ unsigned umin32(unsigned a, unsigned b) {
    return a < b ? a : b;
}

// One fused kernel. Block = one graph slice: preps all 512 nodes of its graph
// into LDS (coords + pad/global-biased |x|^2 per channel), then each of the 8
// waves computes one row's 512 distances from LDS and selects top-9 in-wave
// on 32-bit quantized keys. Static edge lists written by the first blocks.
// NOTE: this is the measured-best structure (73.2 us). Two restructurings
// (coalesced float4 staging; 2-waves/row split with 1024 blocks) both
// regressed (+2.3 / +6.6 us) — per-block whole-graph staging means grid
// growth multiplies staging work, and the scalar prep loads were already
// L2-resident and latency-hidden at 16 waves/CU.
__global__ __launch_bounds__(TPB, 4) void fused_kernel(const float* __restrict__ X,
                                                       const int* __restrict__ AP,
                                                       const int* __restrict__ S,
                                                       const int* __restrict__ sec,
                                                       float* __restrict__ out) {
    __shared__ float4 ch[C_][L_];   // per channel: (x, y, z, sq + masks)  = 48 KB

    const int tid = threadIdx.x;
    const int lane = tid & 63;
    const int wv = tid >> 6;
    const int row = blockIdx.x * RPB + wv;
    const int base = row & ~(L_ - 1);
    const int rl = row & (L_ - 1);

    // ---- static glb/seq edge lists (first 32 blocks' threads) ----
    {
        const int gt = blockIdx.x * TPB + tid;
        if (gt < GLB_TOT) {
            const int r = gt / (B_ * GLB_PER);
            const int rem = gt % (B_ * GLB_PER);
            const int b = rem / GLB_PER;
            const int q = rem % GLB_PER;
            int v;
            if (r == 0) v = (q < L_) ? 0 : (q - (L_ - 1));   // src: [0]*L ++ [1..L-1]
            else        v = (q < L_) ? q : 0;                // dst: [0..L-1] ++ [0]*(L-1)
            out[OFF_GLB + gt] = (float)(v + b * L_);
        }
        if (gt < SEQ_TOT) {
            const int r = gt / (B_ * SEQ_PER);
            const int rem = gt % (B_ * SEQ_PER);
            const int b = rem / SEQ_PER;
            const int q = rem % SEQ_PER;
            int v;
            if (r == 0) v = (q < L_ - 2) ? (q + 1) : (q - (L_ - 2) + 2);  // [1..510]++[2..511]
            else        v = (q < L_ - 2) ? (q + 2) : (q - (L_ - 2) + 1);  // [2..511]++[1..510]
            out[OFF_SEQ + gt] = (float)(v + b * L_);
        }
    }

    // ---- prep: thread t packs node (base+t) of this block's graph into LDS ----
    {
        const int node = base + tid;
        const float* x = X + (size_t)node * (C_ * 3);
        const float bias_g = (S[node] == 0) ? BIGF : 0.0f;
#pragma unroll
        for (int c = 0; c < C_; ++c) {
            const float a = x[c * 3], b = x[c * 3 + 1], d = x[c * 3 + 2];
            float sq = (a * a + b * b) + d * d;
            if (AP[node * C_ + c] == 0) sq += BIGF;  // padded channel loses every min
            ch[c][tid] = make_float4(a, b, d, sq + bias_g);
        }
    }
    __syncthreads();

    // ---- row fragment: broadcast-read own record, fold -2 into coords ----
    float ax[C_], ay[C_], az[C_], sc[C_];
#pragma unroll
    for (int c = 0; c < C_; ++c) {
        const float4 q = ch[c][rl];
        ax[c] = -2.0f * q.x; ay[c] = -2.0f * q.y; az[c] = -2.0f * q.z;
        sc[c] = q.w;
    }

    // ---- distances: lane j owns cols {j, 64+j, ..., 448+j} ----
    unsigned v[8];
#pragma unroll
    for (int s = 0; s < 8; ++s) {
        const int col = s * 64 + lane;
        float m = 3.0e38f;
#pragma unroll
        for (int d = 0; d < C_; ++d) {
            const float4 q = ch[d][col];
            float md = 3.0e38f;
#pragma unroll
            for (int c = 0; c < C_; ++c) {
                const float val = fmaf(az[c], q.z, fmaf(ay[c], q.y, fmaf(ax[c], q.x, sc[c])));
                md = fminf(md, val);
            }
            m = fminf(m, md + q.w);
        }
        m = fmaxf(m, 0.0f);   // d2, clamped; masked pairs land >= ~1e10
        // 23-bit value prefix + 9-bit col: u32 order == (d2, col) lexicographic
        v[s] = (__float_as_uint(m) & 0xFFFFFE00u) | (unsigned)col;
    }

    // ---- 9 rounds of stable wave argmin on u32 keys ----
    unsigned mine = 0xFFFFFFFFu;
#pragma unroll
    for (int t = 0; t < K_; ++t) {
        unsigned loc = v[0];
#pragma unroll
        for (int s = 1; s < 8; ++s) loc = umin32(loc, v[s]);
#pragma unroll
        for (int off = 32; off >= 1; off >>= 1) {
            const unsigned o = (unsigned)__shfl_xor((int)loc, off, 64);
            loc = umin32(loc, o);
        }
        if (lane == t) mine = loc;                 // lane t keeps round-t winner
#pragma unroll
        for (int s = 0; s < 8; ++s)                // remove winner (keys unique)
            v[s] = (v[s] == loc) ? 0xFFFFFFFFu : v[s];
    }

    // ---- epilogue: lanes 0..8 write the 4 per-edge outputs ----
    if (lane < K_) {
        const int col = (int)(mine & 511u);
        const float d2 = __uint_as_float(mine & 0xFFFFFE00u);
        const bool masked = (d2 >= 1.0e9f);        // valid pairs are < ~1e5
        const float dval = masked ? BIGF : sqrtf(d2);
        const int dst = base + col;
        const bool valid = !masked && (sec[row] == sec[dst]);
        const size_t o = (size_t)row * K_ + lane;
        out[OFF_DKNN + o]  = dval;
        out[OFF_SRC + o]   = (float)row;
        out[OFF_DST + o]   = valid ? (float)dst : -1.0f;
        out[OFF_VALID + o] = valid ? 1.0f : 0.0f;
    }
}

extern "C" void kernel_launch(void* const* d_in, const int* in_sizes, int n_in,
                              void* d_out, int out_size, void* d_ws, size_t ws_size,
                              hipStream_t stream) {
    (void)in_sizes; (void)n_in; (void)out_size; (void)d_ws; (void)ws_size;
    const float* X   = (const float*)d_in[0];
    const int*   AP  = (const int*)d_in[1];
    const int*   S   = (const int*)d_in[2];
    const int*   sec = (const int*)d_in[3];
    float* out = (float*)d_out;

    hipLaunchKernelGGL(fused_kernel, dim3(N_ / RPB), dim3(TPB), 0, stream,
                       X, AP, S, sec, out);
}